// Round 4
// baseline (6757.542 us; speedup 1.0000x reference)
//
#include <hip/hip_runtime.h>
#include <math.h>

#define N_V    100000
#define N_E    200000
#define NNZ_C  1600000
#define NFEAT  128
#define NHID   64
#define NCLASS 40
#define NLAYER 8
#define ALPHA  0.1f

// ---------------------------------------------------------------------------
// counts[e] += 1 for each incidence
__global__ __launch_bounds__(256) void k_count(const int* __restrict__ edges,
                                               int* __restrict__ counts) {
    int z = blockIdx.x * blockDim.x + threadIdx.x;
    if (z < NNZ_C) atomicAdd(&counts[edges[z]], 1);
}

// factorE[e] = degE[e] / counts[e]  (scatter-mean denom folded with degE)
__global__ __launch_bounds__(256) void k_factor(const int* __restrict__ counts,
                                                const float* __restrict__ degE,
                                                float* __restrict__ factorE) {
    int e = blockIdx.x * blockDim.x + threadIdx.x;
    if (e < N_E) {
        int c = counts[e];
        factorE[e] = (c > 0) ? degE[e] / (float)c : 0.0f;
    }
}

// h = relu(x @ W0 + b0); also copy to h0. One wave per row, lane = feature.
__global__ __launch_bounds__(256) void k_lin(const float* __restrict__ x,
                                             const float* __restrict__ W0,
                                             const float* __restrict__ b0,
                                             float* __restrict__ h,
                                             float* __restrict__ h0) {
    __shared__ float sW[NFEAT * NHID];   // 32 KB
    __shared__ float sb[NHID];
    for (int i = threadIdx.x; i < NFEAT * NHID; i += blockDim.x) sW[i] = W0[i];
    if (threadIdx.x < NHID) sb[threadIdx.x] = b0[threadIdx.x];
    __syncthreads();
    const int wid = threadIdx.x >> 6;
    const int f   = threadIdx.x & 63;
    const int wpb = blockDim.x >> 6;
    for (int n = blockIdx.x * wpb + wid; n < N_V; n += gridDim.x * wpb) {
        const float* xr = x + (size_t)n * NFEAT;
        float acc = sb[f];
        #pragma unroll 8
        for (int k = 0; k < NFEAT; ++k) acc = fmaf(xr[k], sW[k * NHID + f], acc);
        float r = fmaxf(acc, 0.0f);
        h [(size_t)n * NHID + f] = r;
        h0[(size_t)n * NHID + f] = r;
    }
}

// Xe[edges[z]] += h[vertex[z]]   (wave per incidence, lane = feature)
__global__ __launch_bounds__(256) void k_scatter_ve(const int* __restrict__ vertex,
                                                    const int* __restrict__ edges,
                                                    const float* __restrict__ h,
                                                    float* __restrict__ Xe) {
    int t = blockIdx.x * blockDim.x + threadIdx.x;
    int z = t >> 6;
    int f = t & 63;
    if (z < NNZ_C) {
        int v = vertex[z];
        int e = edges[z];
        atomicAdd(&Xe[(size_t)e * NHID + f], h[(size_t)v * NHID + f]);
    }
}

// Xv[vertex[z]] += Xe[edges[z]] * factorE[edges[z]]
__global__ __launch_bounds__(256) void k_scatter_ev(const int* __restrict__ vertex,
                                                    const int* __restrict__ edges,
                                                    const float* __restrict__ Xe,
                                                    const float* __restrict__ factorE,
                                                    float* __restrict__ Xv) {
    int t = blockIdx.x * blockDim.x + threadIdx.x;
    int z = t >> 6;
    int f = t & 63;
    if (z < NNZ_C) {
        int v = vertex[z];
        int e = edges[z];
        float val = Xe[(size_t)e * NHID + f] * factorE[e];
        atomicAdd(&Xv[(size_t)v * NHID + f], val);
    }
}

// Per-vertex: scale by degV, L2 row-normalize, GCNII mix, 64x64 GEMM, relu.
// One wave per row, lane = feature. Ws tile in LDS (16 KB).
__global__ __launch_bounds__(256) void k_update(const float* __restrict__ Xv,
                                                const float* __restrict__ degV,
                                                const float* __restrict__ h0,
                                                const float* __restrict__ Wi,
                                                float beta,
                                                float* __restrict__ h) {
    __shared__ float sW[NHID * NHID];    // 16 KB
    for (int i = threadIdx.x; i < NHID * NHID; i += blockDim.x) sW[i] = Wi[i];
    __syncthreads();
    const int wid = threadIdx.x >> 6;
    const int f   = threadIdx.x & 63;
    const int wpb = blockDim.x >> 6;
    for (int n = blockIdx.x * wpb + wid; n < N_V; n += gridDim.x * wpb) {
        // Xv * degV FIRST, then the norm is taken of the scaled row (matches ref)
        float xv = Xv[(size_t)n * NHID + f] * degV[n];
        float ss = xv * xv;
        #pragma unroll
        for (int off = 32; off > 0; off >>= 1) ss += __shfl_xor(ss, off, 64);
        float rn  = sqrtf(ss);
        float inv = (rn > 0.0f) ? 1.0f / rn : 0.0f;
        float xi  = (1.0f - ALPHA) * (xv * inv) + ALPHA * h0[(size_t)n * NHID + f];
        // y_f = sum_k xi_k * Ws[k][f] ; broadcast xi_k via shuffle
        float y = 0.0f;
        #pragma unroll 8
        for (int k = 0; k < NHID; ++k)
            y = fmaf(__shfl(xi, k, 64), sW[k * NHID + f], y);
        // (1-beta)*xi + beta*y = xi + beta*(y - xi)
        float o = fmaf(beta, y - xi, xi);
        h[(size_t)n * NHID + f] = fmaxf(o, 0.0f);
    }
}

// out = h @ Wout + bout. One wave per row; lanes 0..39 hold the classes.
__global__ __launch_bounds__(256) void k_out(const float* __restrict__ h,
                                             const float* __restrict__ Wout,
                                             const float* __restrict__ bout,
                                             float* __restrict__ out) {
    __shared__ float sW[NHID * NCLASS];  // 10 KB
    __shared__ float sb[NCLASS];
    for (int i = threadIdx.x; i < NHID * NCLASS; i += blockDim.x) sW[i] = Wout[i];
    if (threadIdx.x < NCLASS) sb[threadIdx.x] = bout[threadIdx.x];
    __syncthreads();
    const int wid = threadIdx.x >> 6;
    const int f   = threadIdx.x & 63;
    const int wpb = blockDim.x >> 6;
    const int c   = (f < NCLASS) ? f : 0;   // lanes >= 40 compute a dummy col
    for (int n = blockIdx.x * wpb + wid; n < N_V; n += gridDim.x * wpb) {
        float hv = h[(size_t)n * NHID + f];
        float y  = sb[c];
        #pragma unroll 8
        for (int k = 0; k < NHID; ++k)
            y = fmaf(__shfl(hv, k, 64), sW[k * NCLASS + c], y);
        if (f < NCLASS) out[(size_t)n * NCLASS + f] = y;
    }
}

// ---------------------------------------------------------------------------
extern "C" void kernel_launch(void* const* d_in, const int* in_sizes, int n_in,
                              void* d_out, int out_size, void* d_ws, size_t ws_size,
                              hipStream_t stream) {
    const float* x      = (const float*)d_in[0];
    const int*   vertex = (const int*)  d_in[1];
    const int*   edges  = (const int*)  d_in[2];
    const float* degE   = (const float*)d_in[3];
    const float* degV   = (const float*)d_in[4];
    const float* W0     = (const float*)d_in[5];
    const float* b0     = (const float*)d_in[6];
    const float* Ws     = (const float*)d_in[7];
    const float* Wout   = (const float*)d_in[8];
    const float* bout   = (const float*)d_in[9];
    float* out = (float*)d_out;

    // workspace carve-up (all fp32): 129.6 MB total
    char* ws = (char*)d_ws;
    float* h0      = (float*)ws; ws += (size_t)N_V * NHID * sizeof(float);
    float* hA      = (float*)ws; ws += (size_t)N_V * NHID * sizeof(float);
    float* hB      = (float*)ws; ws += (size_t)N_V * NHID * sizeof(float);
    float* Xe      = (float*)ws; ws += (size_t)N_E * NHID * sizeof(float);
    float* factorE = (float*)ws; ws += (size_t)N_E * sizeof(float);
    int*   counts  = (int*)  ws; ws += (size_t)N_E * sizeof(int);

    hipMemsetAsync(counts, 0, (size_t)N_E * sizeof(int), stream);
    k_count <<<(NNZ_C + 255) / 256, 256, 0, stream>>>(edges, counts);
    k_factor<<<(N_E + 255) / 256,   256, 0, stream>>>(counts, degE, factorE);
    k_lin   <<<2048, 256, 0, stream>>>(x, W0, b0, hA, h0);

    const int scatter_blocks = (int)(((long long)NNZ_C * 64 + 255) / 256); // 400000

    for (int i = 0; i < NLAYER; ++i) {
        float beta = (float)log(0.5 / (double)(i + 1) + 1.0);
        hipMemsetAsync(Xe, 0, (size_t)N_E * NHID * sizeof(float), stream);
        hipMemsetAsync(hB, 0, (size_t)N_V * NHID * sizeof(float), stream);
        k_scatter_ve<<<scatter_blocks, 256, 0, stream>>>(vertex, edges, hA, Xe);
        k_scatter_ev<<<scatter_blocks, 256, 0, stream>>>(vertex, edges, Xe, factorE, hB);
        k_update<<<4096, 256, 0, stream>>>(hB, degV, h0,
                                           Ws + (size_t)i * NHID * NHID, beta, hA);
    }
    k_out<<<4096, 256, 0, stream>>>(hA, Wout, bout, out);
}

// Round 5
// 2503.656 us; speedup vs baseline: 2.6991x; 2.6991x over previous
//
#include <hip/hip_runtime.h>
#include <math.h>

#define N_V    100000
#define N_E    200000
#define NNZ_C  1600000
#define NFEAT  128
#define NHID   64
#define NCLASS 40
#define NLAYER 8
#define ALPHA  0.1f

// ---------------------------------------------------------------------------
// histogram incidences per edge AND per vertex
__global__ __launch_bounds__(256) void k_count2(const int* __restrict__ vertex,
                                                const int* __restrict__ edges,
                                                int* __restrict__ cntE,
                                                int* __restrict__ cntV) {
    int z = blockIdx.x * blockDim.x + threadIdx.x;
    if (z < NNZ_C) {
        atomicAdd(&cntE[edges[z]], 1);
        atomicAdd(&cntV[vertex[z]], 1);
    }
}

// exclusive scan over n ints, 1024 elements per block (256 thr x 4 elems)
__global__ __launch_bounds__(256) void k_scan_partial(const int* __restrict__ in,
                                                      int* __restrict__ out,
                                                      int* __restrict__ blockSums,
                                                      int n) {
    __shared__ int sd[256];
    const int t = threadIdx.x;
    const int base = blockIdx.x * 1024 + t * 4;
    int v0 = (base + 0 < n) ? in[base + 0] : 0;
    int v1 = (base + 1 < n) ? in[base + 1] : 0;
    int v2 = (base + 2 < n) ? in[base + 2] : 0;
    int v3 = (base + 3 < n) ? in[base + 3] : 0;
    int s = v0 + v1 + v2 + v3;
    sd[t] = s;
    __syncthreads();
    #pragma unroll
    for (int off = 1; off < 256; off <<= 1) {
        int x = (t >= off) ? sd[t - off] : 0;
        __syncthreads();
        sd[t] += x;
        __syncthreads();
    }
    if (blockSums && t == 255) blockSums[blockIdx.x] = sd[255];
    int run = sd[t] - s;                 // exclusive prefix of this thread
    if (base + 0 < n) out[base + 0] = run; run += v0;
    if (base + 1 < n) out[base + 1] = run; run += v1;
    if (base + 2 < n) out[base + 2] = run; run += v2;
    if (base + 3 < n) out[base + 3] = run;
}

__global__ __launch_bounds__(256) void k_scan_add(int* __restrict__ data,
                                                  const int* __restrict__ bsOff,
                                                  int n) {
    const int base = blockIdx.x * 1024 + threadIdx.x * 4;
    const int add = bsOff[blockIdx.x];
    #pragma unroll
    for (int j = 0; j < 4; ++j)
        if (base + j < n) data[base + j] += add;
}

// factorE = degE / count; also finalize the CSR offset sentinels
__global__ __launch_bounds__(256) void k_factor(const int* __restrict__ counts,
                                                const float* __restrict__ degE,
                                                float* __restrict__ factorE,
                                                int* __restrict__ offE,
                                                int* __restrict__ offV) {
    int e = blockIdx.x * blockDim.x + threadIdx.x;
    if (e == 0) { offE[N_E] = NNZ_C; offV[N_V] = NNZ_C; }
    if (e < N_E) {
        int c = counts[e];
        factorE[e] = (c > 0) ? degE[e] / (float)c : 0.0f;
    }
}

// fill both adjacency lists (cursor order within a segment is arbitrary —
// only perturbs fp-sum rounding, well inside the tolerance)
__global__ __launch_bounds__(256) void k_fill(const int* __restrict__ vertex,
                                              const int* __restrict__ edges,
                                              const int* __restrict__ offE,
                                              const int* __restrict__ offV,
                                              int* __restrict__ curE,
                                              int* __restrict__ curV,
                                              int* __restrict__ adjV,
                                              int* __restrict__ adjE) {
    int z = blockIdx.x * blockDim.x + threadIdx.x;
    if (z < NNZ_C) {
        int v = vertex[z], e = edges[z];
        int pe = atomicAdd(&curE[e], 1);
        adjV[offE[e] + pe] = v;
        int pv = atomicAdd(&curV[v], 1);
        adjE[offV[v] + pv] = e;
    }
}

// h = relu(x @ W0 + b0); also copy to h0. One wave per row, lane = feature.
__global__ __launch_bounds__(256) void k_lin(const float* __restrict__ x,
                                             const float* __restrict__ W0,
                                             const float* __restrict__ b0,
                                             float* __restrict__ h,
                                             float* __restrict__ h0) {
    __shared__ float sW[NFEAT * NHID];   // 32 KB
    __shared__ float sb[NHID];
    for (int i = threadIdx.x; i < NFEAT * NHID; i += blockDim.x) sW[i] = W0[i];
    if (threadIdx.x < NHID) sb[threadIdx.x] = b0[threadIdx.x];
    __syncthreads();
    const int wid = threadIdx.x >> 6;
    const int f   = threadIdx.x & 63;
    const int wpb = blockDim.x >> 6;
    for (int n = blockIdx.x * wpb + wid; n < N_V; n += gridDim.x * wpb) {
        const float* xr = x + (size_t)n * NFEAT;
        float acc = sb[f];
        #pragma unroll 8
        for (int k = 0; k < NFEAT; ++k) acc = fmaf(xr[k], sW[k * NHID + f], acc);
        float r = fmaxf(acc, 0.0f);
        h [(size_t)n * NHID + f] = r;
        h0[(size_t)n * NHID + f] = r;
    }
}

// Xe[e] = (sum over incident vertices of h[v]) * factorE[e]
// one wave per edge, lane = feature; gather reads, ONE coalesced write, no atomics
__global__ __launch_bounds__(256) void k_edge_gather(const int* __restrict__ offE,
                                                     const int* __restrict__ adjV,
                                                     const float* __restrict__ factorE,
                                                     const float* __restrict__ h,
                                                     float* __restrict__ Xe) {
    const int wid = threadIdx.x >> 6;
    const int f   = threadIdx.x & 63;
    const int e   = blockIdx.x * 4 + wid;
    if (e >= N_E) return;
    int s = offE[e], s1 = offE[e + 1];
    float acc = 0.0f;
    for (; s + 4 <= s1; s += 4) {        // batch indices for memory-level parallelism
        int a = adjV[s], b = adjV[s + 1], c = adjV[s + 2], d = adjV[s + 3];
        acc += h[(size_t)a * NHID + f];
        acc += h[(size_t)b * NHID + f];
        acc += h[(size_t)c * NHID + f];
        acc += h[(size_t)d * NHID + f];
    }
    for (; s < s1; ++s) acc += h[(size_t)adjV[s] * NHID + f];
    Xe[(size_t)e * NHID + f] = acc * factorE[e];
}

// Fused: Xv = (sum over incident edges of Xe[e]) * degV  ->  L2 rownorm ->
// GCNII mix -> 64x64 GEMM -> relu. One wave per vertex, lane = feature.
__global__ __launch_bounds__(256) void k_vertex_update(const int* __restrict__ offV,
                                                       const int* __restrict__ adjE,
                                                       const float* __restrict__ Xe,
                                                       const float* __restrict__ degV,
                                                       const float* __restrict__ h0,
                                                       const float* __restrict__ Wi,
                                                       float beta,
                                                       float* __restrict__ h) {
    __shared__ float sW[NHID * NHID];    // 16 KB
    for (int i = threadIdx.x; i < NHID * NHID; i += blockDim.x) sW[i] = Wi[i];
    __syncthreads();
    const int wid = threadIdx.x >> 6;
    const int f   = threadIdx.x & 63;
    const int n   = blockIdx.x * 4 + wid;
    if (n >= N_V) return;
    int s = offV[n], s1 = offV[n + 1];
    float acc = 0.0f;
    for (; s + 4 <= s1; s += 4) {
        int a = adjE[s], b = adjE[s + 1], c = adjE[s + 2], d = adjE[s + 3];
        acc += Xe[(size_t)a * NHID + f];
        acc += Xe[(size_t)b * NHID + f];
        acc += Xe[(size_t)c * NHID + f];
        acc += Xe[(size_t)d * NHID + f];
    }
    for (; s < s1; ++s) acc += Xe[(size_t)adjE[s] * NHID + f];
    // scale by degV FIRST, then norm of the scaled row (matches reference)
    float xv = acc * degV[n];
    float ss = xv * xv;
    #pragma unroll
    for (int off = 32; off > 0; off >>= 1) ss += __shfl_xor(ss, off, 64);
    float rn  = sqrtf(ss);
    float inv = (rn > 0.0f) ? 1.0f / rn : 0.0f;
    float xi  = (1.0f - ALPHA) * (xv * inv) + ALPHA * h0[(size_t)n * NHID + f];
    float y = 0.0f;
    #pragma unroll 8
    for (int k = 0; k < NHID; ++k)
        y = fmaf(__shfl(xi, k, 64), sW[k * NHID + f], y);
    float o = fmaf(beta, y - xi, xi);    // (1-beta)*xi + beta*y
    h[(size_t)n * NHID + f] = fmaxf(o, 0.0f);
}

// out = h @ Wout + bout. One wave per row; lanes 0..39 hold the classes.
__global__ __launch_bounds__(256) void k_out(const float* __restrict__ h,
                                             const float* __restrict__ Wout,
                                             const float* __restrict__ bout,
                                             float* __restrict__ out) {
    __shared__ float sW[NHID * NCLASS];  // 10 KB
    __shared__ float sb[NCLASS];
    for (int i = threadIdx.x; i < NHID * NCLASS; i += blockDim.x) sW[i] = Wout[i];
    if (threadIdx.x < NCLASS) sb[threadIdx.x] = bout[threadIdx.x];
    __syncthreads();
    const int wid = threadIdx.x >> 6;
    const int f   = threadIdx.x & 63;
    const int wpb = blockDim.x >> 6;
    const int c   = (f < NCLASS) ? f : 0;
    for (int n = blockIdx.x * wpb + wid; n < N_V; n += gridDim.x * wpb) {
        float hv = h[(size_t)n * NHID + f];
        float y  = sb[c];
        #pragma unroll 8
        for (int k = 0; k < NHID; ++k)
            y = fmaf(__shfl(hv, k, 64), sW[k * NCLASS + c], y);
        if (f < NCLASS) out[(size_t)n * NCLASS + f] = y;
    }
}

// ---------------------------------------------------------------------------
extern "C" void kernel_launch(void* const* d_in, const int* in_sizes, int n_in,
                              void* d_out, int out_size, void* d_ws, size_t ws_size,
                              hipStream_t stream) {
    const float* x      = (const float*)d_in[0];
    const int*   vertex = (const int*)  d_in[1];
    const int*   edges  = (const int*)  d_in[2];
    const float* degE   = (const float*)d_in[3];
    const float* degV   = (const float*)d_in[4];
    const float* W0     = (const float*)d_in[5];
    const float* b0     = (const float*)d_in[6];
    const float* Ws     = (const float*)d_in[7];
    const float* Wout   = (const float*)d_in[8];
    const float* bout   = (const float*)d_in[9];
    float* out = (float*)d_out;

    // workspace carve-up (~119 MB)
    char* p = (char*)d_ws;
    auto carve = [&](size_t bytes) { char* r = p; p += (bytes + 255) & ~(size_t)255; return r; };
    float* h0      = (float*)carve((size_t)N_V * NHID * sizeof(float));
    float* hA      = (float*)carve((size_t)N_V * NHID * sizeof(float));
    float* Xe      = (float*)carve((size_t)N_E * NHID * sizeof(float));
    float* factorE = (float*)carve((size_t)N_E * sizeof(float));
    int*   offE    = (int*)  carve((size_t)(N_E + 1) * sizeof(int));
    int*   offV    = (int*)  carve((size_t)(N_V + 1) * sizeof(int));
    int*   cntE    = (int*)  carve((size_t)N_E * sizeof(int));   // reused as cursor
    int*   cntV    = (int*)  carve((size_t)N_V * sizeof(int));   // reused as cursor
    int*   adjV    = (int*)  carve((size_t)NNZ_C * sizeof(int));
    int*   adjE    = (int*)  carve((size_t)NNZ_C * sizeof(int));
    int*   bsE     = (int*)  carve(256 * sizeof(int));
    int*   bsOffE  = (int*)  carve(256 * sizeof(int));
    int*   bsV     = (int*)  carve(256 * sizeof(int));
    int*   bsOffV  = (int*)  carve(256 * sizeof(int));

    const int scanBlocksE = (N_E + 1023) / 1024;   // 196
    const int scanBlocksV = (N_V + 1023) / 1024;   // 98

    // ---- one-time CSR build (per call) ----
    hipMemsetAsync(cntE, 0, (size_t)N_E * sizeof(int), stream);
    hipMemsetAsync(cntV, 0, (size_t)N_V * sizeof(int), stream);
    k_count2<<<(NNZ_C + 255) / 256, 256, 0, stream>>>(vertex, edges, cntE, cntV);

    k_scan_partial<<<scanBlocksE, 256, 0, stream>>>(cntE, offE, bsE, N_E);
    k_scan_partial<<<1,           256, 0, stream>>>(bsE, bsOffE, nullptr, scanBlocksE);
    k_scan_add    <<<scanBlocksE, 256, 0, stream>>>(offE, bsOffE, N_E);

    k_scan_partial<<<scanBlocksV, 256, 0, stream>>>(cntV, offV, bsV, N_V);
    k_scan_partial<<<1,           256, 0, stream>>>(bsV, bsOffV, nullptr, scanBlocksV);
    k_scan_add    <<<scanBlocksV, 256, 0, stream>>>(offV, bsOffV, N_V);

    k_factor<<<(N_E + 255) / 256, 256, 0, stream>>>(cntE, degE, factorE, offE, offV);

    hipMemsetAsync(cntE, 0, (size_t)N_E * sizeof(int), stream);
    hipMemsetAsync(cntV, 0, (size_t)N_V * sizeof(int), stream);
    k_fill<<<(NNZ_C + 255) / 256, 256, 0, stream>>>(vertex, edges, offE, offV,
                                                    cntE, cntV, adjV, adjE);

    // ---- network ----
    k_lin<<<2048, 256, 0, stream>>>(x, W0, b0, hA, h0);

    for (int i = 0; i < NLAYER; ++i) {
        float beta = (float)log(0.5 / (double)(i + 1) + 1.0);
        k_edge_gather  <<<(N_E + 3) / 4, 256, 0, stream>>>(offE, adjV, factorE, hA, Xe);
        k_vertex_update<<<(N_V + 3) / 4, 256, 0, stream>>>(offV, adjE, Xe, degV, h0,
                                                           Ws + (size_t)i * NHID * NHID,
                                                           beta, hA);
    }
    k_out<<<4096, 256, 0, stream>>>(hA, Wout, bout, out);
}

// Round 6
// 2410.429 us; speedup vs baseline: 2.8035x; 1.0387x over previous
//
#include <hip/hip_runtime.h>
#include <math.h>

#define N_V    100000
#define N_E    200000
#define NNZ_C  1600000
#define NFEAT  128
#define NHID   64
#define NCLASS 40
#define NLAYER 8
#define ALPHA  0.1f

typedef _Float16 f16;

// ---------------------------------------------------------------------------
// histogram incidences per edge AND per vertex
__global__ __launch_bounds__(256) void k_count2(const int* __restrict__ vertex,
                                                const int* __restrict__ edges,
                                                int* __restrict__ cntE,
                                                int* __restrict__ cntV) {
    int z = blockIdx.x * blockDim.x + threadIdx.x;
    if (z < NNZ_C) {
        atomicAdd(&cntE[edges[z]], 1);
        atomicAdd(&cntV[vertex[z]], 1);
    }
}

// exclusive scan over n ints, 1024 elements per block (256 thr x 4 elems)
__global__ __launch_bounds__(256) void k_scan_partial(const int* __restrict__ in,
                                                      int* __restrict__ out,
                                                      int* __restrict__ blockSums,
                                                      int n) {
    __shared__ int sd[256];
    const int t = threadIdx.x;
    const int base = blockIdx.x * 1024 + t * 4;
    int v0 = (base + 0 < n) ? in[base + 0] : 0;
    int v1 = (base + 1 < n) ? in[base + 1] : 0;
    int v2 = (base + 2 < n) ? in[base + 2] : 0;
    int v3 = (base + 3 < n) ? in[base + 3] : 0;
    int s = v0 + v1 + v2 + v3;
    sd[t] = s;
    __syncthreads();
    #pragma unroll
    for (int off = 1; off < 256; off <<= 1) {
        int x = (t >= off) ? sd[t - off] : 0;
        __syncthreads();
        sd[t] += x;
        __syncthreads();
    }
    if (blockSums && t == 255) blockSums[blockIdx.x] = sd[255];
    int run = sd[t] - s;                 // exclusive prefix of this thread
    if (base + 0 < n) out[base + 0] = run; run += v0;
    if (base + 1 < n) out[base + 1] = run; run += v1;
    if (base + 2 < n) out[base + 2] = run; run += v2;
    if (base + 3 < n) out[base + 3] = run;
}

__global__ __launch_bounds__(256) void k_scan_add(int* __restrict__ data,
                                                  const int* __restrict__ bsOff,
                                                  int n) {
    const int base = blockIdx.x * 1024 + threadIdx.x * 4;
    const int add = bsOff[blockIdx.x];
    #pragma unroll
    for (int j = 0; j < 4; ++j)
        if (base + j < n) data[base + j] += add;
}

// factorE = degE / count; also finalize the CSR offset sentinels
__global__ __launch_bounds__(256) void k_factor(const int* __restrict__ counts,
                                                const float* __restrict__ degE,
                                                float* __restrict__ factorE,
                                                int* __restrict__ offE,
                                                int* __restrict__ offV) {
    int e = blockIdx.x * blockDim.x + threadIdx.x;
    if (e == 0) { offE[N_E] = NNZ_C; offV[N_V] = NNZ_C; }
    if (e < N_E) {
        int c = counts[e];
        factorE[e] = (c > 0) ? degE[e] / (float)c : 0.0f;
    }
}

// fill both adjacency lists (cursor order within a segment is arbitrary —
// only perturbs fp-sum rounding, well inside the tolerance)
__global__ __launch_bounds__(256) void k_fill(const int* __restrict__ vertex,
                                              const int* __restrict__ edges,
                                              const int* __restrict__ offE,
                                              const int* __restrict__ offV,
                                              int* __restrict__ curE,
                                              int* __restrict__ curV,
                                              int* __restrict__ adjV,
                                              int* __restrict__ adjE) {
    int z = blockIdx.x * blockDim.x + threadIdx.x;
    if (z < NNZ_C) {
        int v = vertex[z], e = edges[z];
        int pe = atomicAdd(&curE[e], 1);
        adjV[offE[e] + pe] = v;
        int pv = atomicAdd(&curV[v], 1);
        adjE[offV[v] + pv] = e;
    }
}

// h = relu(x @ W0 + b0) -> fp16; also copy to h0. One wave per row, lane = feature.
__global__ __launch_bounds__(256) void k_lin(const float* __restrict__ x,
                                             const float* __restrict__ W0,
                                             const float* __restrict__ b0,
                                             f16* __restrict__ h,
                                             f16* __restrict__ h0) {
    __shared__ float sW[NFEAT * NHID];   // 32 KB
    __shared__ float sb[NHID];
    for (int i = threadIdx.x; i < NFEAT * NHID; i += blockDim.x) sW[i] = W0[i];
    if (threadIdx.x < NHID) sb[threadIdx.x] = b0[threadIdx.x];
    __syncthreads();
    const int wid = threadIdx.x >> 6;
    const int f   = threadIdx.x & 63;
    const int wpb = blockDim.x >> 6;
    for (int n = blockIdx.x * wpb + wid; n < N_V; n += gridDim.x * wpb) {
        const float* xr = x + (size_t)n * NFEAT;
        float acc = sb[f];
        #pragma unroll 8
        for (int k = 0; k < NFEAT; ++k) acc = fmaf(xr[k], sW[k * NHID + f], acc);
        f16 r = (f16)fmaxf(acc, 0.0f);
        h [(size_t)n * NHID + f] = r;
        h0[(size_t)n * NHID + f] = r;
    }
}

// Xe[e] = (sum over incident vertices of h[v]) * factorE[e]   (fp16 in/out, fp32 acc)
__global__ __launch_bounds__(256) void k_edge_gather(const int* __restrict__ offE,
                                                     const int* __restrict__ adjV,
                                                     const float* __restrict__ factorE,
                                                     const f16* __restrict__ h,
                                                     f16* __restrict__ Xe) {
    const int wid = threadIdx.x >> 6;
    const int f   = threadIdx.x & 63;
    const int e   = blockIdx.x * 4 + wid;
    if (e >= N_E) return;
    int s = offE[e], s1 = offE[e + 1];
    float acc = 0.0f;
    for (; s + 4 <= s1; s += 4) {        // batch indices for memory-level parallelism
        int a = adjV[s], b = adjV[s + 1], c = adjV[s + 2], d = adjV[s + 3];
        acc += (float)h[(size_t)a * NHID + f];
        acc += (float)h[(size_t)b * NHID + f];
        acc += (float)h[(size_t)c * NHID + f];
        acc += (float)h[(size_t)d * NHID + f];
    }
    for (; s < s1; ++s) acc += (float)h[(size_t)adjV[s] * NHID + f];
    Xe[(size_t)e * NHID + f] = (f16)(acc * factorE[e]);
}

// Fused: Xv = (sum over incident edges of Xe[e]) * degV  ->  L2 rownorm ->
// GCNII mix -> 64x64 GEMM -> relu -> fp16. One wave per vertex, lane = feature.
__global__ __launch_bounds__(256) void k_vertex_update(const int* __restrict__ offV,
                                                       const int* __restrict__ adjE,
                                                       const f16* __restrict__ Xe,
                                                       const float* __restrict__ degV,
                                                       const f16* __restrict__ h0,
                                                       const float* __restrict__ Wi,
                                                       float beta,
                                                       f16* __restrict__ h) {
    __shared__ float sW[NHID * NHID];    // 16 KB
    for (int i = threadIdx.x; i < NHID * NHID; i += blockDim.x) sW[i] = Wi[i];
    __syncthreads();
    const int wid = threadIdx.x >> 6;
    const int f   = threadIdx.x & 63;
    const int n   = blockIdx.x * 4 + wid;
    if (n >= N_V) return;
    int s = offV[n], s1 = offV[n + 1];
    float acc = 0.0f;
    for (; s + 4 <= s1; s += 4) {
        int a = adjE[s], b = adjE[s + 1], c = adjE[s + 2], d = adjE[s + 3];
        acc += (float)Xe[(size_t)a * NHID + f];
        acc += (float)Xe[(size_t)b * NHID + f];
        acc += (float)Xe[(size_t)c * NHID + f];
        acc += (float)Xe[(size_t)d * NHID + f];
    }
    for (; s < s1; ++s) acc += (float)Xe[(size_t)adjE[s] * NHID + f];
    // scale by degV FIRST, then norm of the scaled row (matches reference)
    float xv = acc * degV[n];
    float ss = xv * xv;
    #pragma unroll
    for (int off = 32; off > 0; off >>= 1) ss += __shfl_xor(ss, off, 64);
    float rn  = sqrtf(ss);
    float inv = (rn > 0.0f) ? 1.0f / rn : 0.0f;
    float xi  = (1.0f - ALPHA) * (xv * inv) + ALPHA * (float)h0[(size_t)n * NHID + f];
    float y = 0.0f;
    #pragma unroll 8
    for (int k = 0; k < NHID; ++k)
        y = fmaf(__shfl(xi, k, 64), sW[k * NHID + f], y);
    float o = fmaf(beta, y - xi, xi);    // (1-beta)*xi + beta*y
    h[(size_t)n * NHID + f] = (f16)fmaxf(o, 0.0f);
}

// out = h @ Wout + bout. One wave per row; lanes 0..39 hold the classes.
__global__ __launch_bounds__(256) void k_out(const f16* __restrict__ h,
                                             const float* __restrict__ Wout,
                                             const float* __restrict__ bout,
                                             float* __restrict__ out) {
    __shared__ float sW[NHID * NCLASS];  // 10 KB
    __shared__ float sb[NCLASS];
    for (int i = threadIdx.x; i < NHID * NCLASS; i += blockDim.x) sW[i] = Wout[i];
    if (threadIdx.x < NCLASS) sb[threadIdx.x] = bout[threadIdx.x];
    __syncthreads();
    const int wid = threadIdx.x >> 6;
    const int f   = threadIdx.x & 63;
    const int wpb = blockDim.x >> 6;
    const int c   = (f < NCLASS) ? f : 0;
    for (int n = blockIdx.x * wpb + wid; n < N_V; n += gridDim.x * wpb) {
        float hv = (float)h[(size_t)n * NHID + f];
        float y  = sb[c];
        #pragma unroll 8
        for (int k = 0; k < NHID; ++k)
            y = fmaf(__shfl(hv, k, 64), sW[k * NCLASS + c], y);
        if (f < NCLASS) out[(size_t)n * NCLASS + f] = y;
    }
}

// ---------------------------------------------------------------------------
extern "C" void kernel_launch(void* const* d_in, const int* in_sizes, int n_in,
                              void* d_out, int out_size, void* d_ws, size_t ws_size,
                              hipStream_t stream) {
    const float* x      = (const float*)d_in[0];
    const int*   vertex = (const int*)  d_in[1];
    const int*   edges  = (const int*)  d_in[2];
    const float* degE   = (const float*)d_in[3];
    const float* degV   = (const float*)d_in[4];
    const float* W0     = (const float*)d_in[5];
    const float* b0     = (const float*)d_in[6];
    const float* Ws     = (const float*)d_in[7];
    const float* Wout   = (const float*)d_in[8];
    const float* bout   = (const float*)d_in[9];
    float* out = (float*)d_out;

    // workspace carve-up (~66 MB)
    char* p = (char*)d_ws;
    auto carve = [&](size_t bytes) { char* r = p; p += (bytes + 255) & ~(size_t)255; return r; };
    f16*   h0      = (f16*)  carve((size_t)N_V * NHID * sizeof(f16));
    f16*   hA      = (f16*)  carve((size_t)N_V * NHID * sizeof(f16));
    f16*   Xe      = (f16*)  carve((size_t)N_E * NHID * sizeof(f16));
    float* factorE = (float*)carve((size_t)N_E * sizeof(float));
    int*   offE    = (int*)  carve((size_t)(N_E + 1) * sizeof(int));
    int*   offV    = (int*)  carve((size_t)(N_V + 1) * sizeof(int));
    int*   cntE    = (int*)  carve((size_t)N_E * sizeof(int));   // reused as cursor
    int*   cntV    = (int*)  carve((size_t)N_V * sizeof(int));   // reused as cursor
    int*   adjV    = (int*)  carve((size_t)NNZ_C * sizeof(int));
    int*   adjE    = (int*)  carve((size_t)NNZ_C * sizeof(int));
    int*   bsE     = (int*)  carve(256 * sizeof(int));
    int*   bsOffE  = (int*)  carve(256 * sizeof(int));
    int*   bsV     = (int*)  carve(256 * sizeof(int));
    int*   bsOffV  = (int*)  carve(256 * sizeof(int));

    const int scanBlocksE = (N_E + 1023) / 1024;   // 196
    const int scanBlocksV = (N_V + 1023) / 1024;   // 98

    // ---- one-time CSR build (per call) ----
    hipMemsetAsync(cntE, 0, (size_t)N_E * sizeof(int), stream);
    hipMemsetAsync(cntV, 0, (size_t)N_V * sizeof(int), stream);
    k_count2<<<(NNZ_C + 255) / 256, 256, 0, stream>>>(vertex, edges, cntE, cntV);

    k_scan_partial<<<scanBlocksE, 256, 0, stream>>>(cntE, offE, bsE, N_E);
    k_scan_partial<<<1,           256, 0, stream>>>(bsE, bsOffE, nullptr, scanBlocksE);
    k_scan_add    <<<scanBlocksE, 256, 0, stream>>>(offE, bsOffE, N_E);

    k_scan_partial<<<scanBlocksV, 256, 0, stream>>>(cntV, offV, bsV, N_V);
    k_scan_partial<<<1,           256, 0, stream>>>(bsV, bsOffV, nullptr, scanBlocksV);
    k_scan_add    <<<scanBlocksV, 256, 0, stream>>>(offV, bsOffV, N_V);

    k_factor<<<(N_E + 255) / 256, 256, 0, stream>>>(cntE, degE, factorE, offE, offV);

    hipMemsetAsync(cntE, 0, (size_t)N_E * sizeof(int), stream);
    hipMemsetAsync(cntV, 0, (size_t)N_V * sizeof(int), stream);
    k_fill<<<(NNZ_C + 255) / 256, 256, 0, stream>>>(vertex, edges, offE, offV,
                                                    cntE, cntV, adjV, adjE);

    // ---- network ----
    k_lin<<<2048, 256, 0, stream>>>(x, W0, b0, hA, h0);

    for (int i = 0; i < NLAYER; ++i) {
        float beta = (float)log(0.5 / (double)(i + 1) + 1.0);
        k_edge_gather  <<<(N_E + 3) / 4, 256, 0, stream>>>(offE, adjV, factorE, hA, Xe);
        k_vertex_update<<<(N_V + 3) / 4, 256, 0, stream>>>(offV, adjE, Xe, degV, h0,
                                                           Ws + (size_t)i * NHID * NHID,
                                                           beta, hA);
    }
    k_out<<<4096, 256, 0, stream>>>(hA, Wout, bout, out);
}

// Round 7
// 2012.225 us; speedup vs baseline: 3.3582x; 1.1979x over previous
//
#include <hip/hip_runtime.h>
#include <math.h>

#define N_V    100000
#define N_E    200000
#define NNZ_C  1600000
#define NFEAT  128
#define NHID   64
#define NCLASS 40
#define NLAYER 8
#define ALPHA  0.1f

typedef _Float16 f16;
typedef _Float16 f16x4 __attribute__((ext_vector_type(4)));

// ---------------------------------------------------------------------------
// histogram incidences per edge AND per vertex
__global__ __launch_bounds__(256) void k_count2(const int* __restrict__ vertex,
                                                const int* __restrict__ edges,
                                                int* __restrict__ cntE,
                                                int* __restrict__ cntV) {
    int z = blockIdx.x * blockDim.x + threadIdx.x;
    if (z < NNZ_C) {
        atomicAdd(&cntE[edges[z]], 1);
        atomicAdd(&cntV[vertex[z]], 1);
    }
}

// exclusive scan over n ints, 1024 elements per block (256 thr x 4 elems)
__global__ __launch_bounds__(256) void k_scan_partial(const int* __restrict__ in,
                                                      int* __restrict__ out,
                                                      int* __restrict__ blockSums,
                                                      int n) {
    __shared__ int sd[256];
    const int t = threadIdx.x;
    const int base = blockIdx.x * 1024 + t * 4;
    int v0 = (base + 0 < n) ? in[base + 0] : 0;
    int v1 = (base + 1 < n) ? in[base + 1] : 0;
    int v2 = (base + 2 < n) ? in[base + 2] : 0;
    int v3 = (base + 3 < n) ? in[base + 3] : 0;
    int s = v0 + v1 + v2 + v3;
    sd[t] = s;
    __syncthreads();
    #pragma unroll
    for (int off = 1; off < 256; off <<= 1) {
        int x = (t >= off) ? sd[t - off] : 0;
        __syncthreads();
        sd[t] += x;
        __syncthreads();
    }
    if (blockSums && t == 255) blockSums[blockIdx.x] = sd[255];
    int run = sd[t] - s;                 // exclusive prefix of this thread
    if (base + 0 < n) out[base + 0] = run; run += v0;
    if (base + 1 < n) out[base + 1] = run; run += v1;
    if (base + 2 < n) out[base + 2] = run; run += v2;
    if (base + 3 < n) out[base + 3] = run;
}

__global__ __launch_bounds__(256) void k_scan_add(int* __restrict__ data,
                                                  const int* __restrict__ bsOff,
                                                  int n) {
    const int base = blockIdx.x * 1024 + threadIdx.x * 4;
    const int add = bsOff[blockIdx.x];
    #pragma unroll
    for (int j = 0; j < 4; ++j)
        if (base + j < n) data[base + j] += add;
}

// factorE = degE / count; also finalize the CSR offset sentinels
__global__ __launch_bounds__(256) void k_factor(const int* __restrict__ counts,
                                                const float* __restrict__ degE,
                                                float* __restrict__ factorE,
                                                int* __restrict__ offE,
                                                int* __restrict__ offV) {
    int e = blockIdx.x * blockDim.x + threadIdx.x;
    if (e == 0) { offE[N_E] = NNZ_C; offV[N_V] = NNZ_C; }
    if (e < N_E) {
        int c = counts[e];
        factorE[e] = (c > 0) ? degE[e] / (float)c : 0.0f;
    }
}

// fill both adjacency lists (cursor order within a segment is arbitrary —
// only perturbs fp-sum rounding, well inside the tolerance)
__global__ __launch_bounds__(256) void k_fill(const int* __restrict__ vertex,
                                              const int* __restrict__ edges,
                                              const int* __restrict__ offE,
                                              const int* __restrict__ offV,
                                              int* __restrict__ curE,
                                              int* __restrict__ curV,
                                              int* __restrict__ adjV,
                                              int* __restrict__ adjE) {
    int z = blockIdx.x * blockDim.x + threadIdx.x;
    if (z < NNZ_C) {
        int v = vertex[z], e = edges[z];
        int pe = atomicAdd(&curE[e], 1);
        adjV[offE[e] + pe] = v;
        int pv = atomicAdd(&curV[v], 1);
        adjE[offV[v] + pv] = e;
    }
}

// h = relu(x @ W0 + b0) -> fp16; also copy to h0. One wave per row, lane = feature.
__global__ __launch_bounds__(256) void k_lin(const float* __restrict__ x,
                                             const float* __restrict__ W0,
                                             const float* __restrict__ b0,
                                             f16* __restrict__ h,
                                             f16* __restrict__ h0) {
    __shared__ float sW[NFEAT * NHID];   // 32 KB
    __shared__ float sb[NHID];
    for (int i = threadIdx.x; i < NFEAT * NHID; i += blockDim.x) sW[i] = W0[i];
    if (threadIdx.x < NHID) sb[threadIdx.x] = b0[threadIdx.x];
    __syncthreads();
    const int wid = threadIdx.x >> 6;
    const int f   = threadIdx.x & 63;
    const int wpb = blockDim.x >> 6;
    for (int n = blockIdx.x * wpb + wid; n < N_V; n += gridDim.x * wpb) {
        const float* xr = x + (size_t)n * NFEAT;
        float acc = sb[f];
        #pragma unroll 8
        for (int k = 0; k < NFEAT; ++k) acc = fmaf(xr[k], sW[k * NHID + f], acc);
        f16 r = (f16)fmaxf(acc, 0.0f);
        h [(size_t)n * NHID + f] = r;
        h0[(size_t)n * NHID + f] = r;
    }
}

// Xe[e] = (sum over incident vertices of h[v]) * factorE[e]
// One wave per edge. Lane = (group g = lane>>4, slot t = lane&15); each lane
// loads an f16x4 (8 B), so the wave gathers 4 rows per load instruction
// (8 with the 2x unroll). Segment reduce across groups via shfl_xor.
__global__ __launch_bounds__(256) void k_edge_gather(const int* __restrict__ offE,
                                                     const int* __restrict__ adjV,
                                                     const float* __restrict__ factorE,
                                                     const f16* __restrict__ h,
                                                     f16* __restrict__ Xe) {
    const int lane = threadIdx.x & 63;
    const int g = lane >> 4, t = lane & 15;
    const int e = blockIdx.x * 4 + (threadIdx.x >> 6);
    if (e >= N_E) return;
    const f16x4* __restrict__ hv = (const f16x4*)h;
    int s = offE[e], s1 = offE[e + 1];
    float acc[4] = {0.f, 0.f, 0.f, 0.f};
    for (; s + 8 <= s1; s += 8) {               // 8 rows in flight per wave
        int ia = adjV[s + g];
        int ib = adjV[s + 4 + g];
        f16x4 va = hv[(size_t)ia * 16 + t];
        f16x4 vb = hv[(size_t)ib * 16 + t];
        #pragma unroll
        for (int j = 0; j < 4; ++j) acc[j] += (float)va[j] + (float)vb[j];
    }
    if (s + 4 <= s1) {
        int ia = adjV[s + g];
        f16x4 va = hv[(size_t)ia * 16 + t];
        #pragma unroll
        for (int j = 0; j < 4; ++j) acc[j] += (float)va[j];
        s += 4;
    }
    if (g < s1 - s) {                            // 0..3 leftover rows
        int ia = adjV[s + g];
        f16x4 va = hv[(size_t)ia * 16 + t];
        #pragma unroll
        for (int j = 0; j < 4; ++j) acc[j] += (float)va[j];
    }
    #pragma unroll
    for (int j = 0; j < 4; ++j) {                // reduce the 4 groups
        acc[j] += __shfl_xor(acc[j], 16, 64);
        acc[j] += __shfl_xor(acc[j], 32, 64);
    }
    float fac = factorE[e];
    if (g == 0) {                                // 16 lanes x 8 B = one row
        f16x4 o;
        #pragma unroll
        for (int j = 0; j < 4; ++j) o[j] = (f16)(acc[j] * fac);
        ((f16x4*)Xe)[(size_t)e * 16 + t] = o;
    }
}

// Fused: Xv = (sum over incident edges of Xe[e]) * degV  ->  L2 rownorm ->
// GCNII mix -> 64x64 GEMM -> relu -> fp16. One wave per vertex, same
// (g,t) lane layout; GEMM splits k = 16g + m across the 4 groups.
__global__ __launch_bounds__(256) void k_vertex_update(const int* __restrict__ offV,
                                                       const int* __restrict__ adjE,
                                                       const f16* __restrict__ Xe,
                                                       const float* __restrict__ degV,
                                                       const f16* __restrict__ h0,
                                                       const float* __restrict__ Wi,
                                                       float beta,
                                                       f16* __restrict__ h) {
    __shared__ float sW[NHID * NHID];    // 16 KB, row-major [k][f]
    for (int i = threadIdx.x; i < NHID * NHID; i += blockDim.x) sW[i] = Wi[i];
    __syncthreads();
    const int lane = threadIdx.x & 63;
    const int g = lane >> 4, t = lane & 15;
    const int n = blockIdx.x * 4 + (threadIdx.x >> 6);
    if (n >= N_V) return;
    const f16x4* __restrict__ xe = (const f16x4*)Xe;
    int s = offV[n], s1 = offV[n + 1];
    float acc[4] = {0.f, 0.f, 0.f, 0.f};
    for (; s + 8 <= s1; s += 8) {
        int ia = adjE[s + g];
        int ib = adjE[s + 4 + g];
        f16x4 va = xe[(size_t)ia * 16 + t];
        f16x4 vb = xe[(size_t)ib * 16 + t];
        #pragma unroll
        for (int j = 0; j < 4; ++j) acc[j] += (float)va[j] + (float)vb[j];
    }
    if (s + 4 <= s1) {
        int ia = adjE[s + g];
        f16x4 va = xe[(size_t)ia * 16 + t];
        #pragma unroll
        for (int j = 0; j < 4; ++j) acc[j] += (float)va[j];
        s += 4;
    }
    if (g < s1 - s) {
        int ia = adjE[s + g];
        f16x4 va = xe[(size_t)ia * 16 + t];
        #pragma unroll
        for (int j = 0; j < 4; ++j) acc[j] += (float)va[j];
    }
    #pragma unroll
    for (int j = 0; j < 4; ++j) {                // reduce groups -> replicated
        acc[j] += __shfl_xor(acc[j], 16, 64);
        acc[j] += __shfl_xor(acc[j], 32, 64);
    }
    // scale by degV FIRST, then norm of the scaled row (matches reference)
    float dv = degV[n];
    float xv[4], ss = 0.f;
    #pragma unroll
    for (int j = 0; j < 4; ++j) { xv[j] = acc[j] * dv; ss += xv[j] * xv[j]; }
    #pragma unroll
    for (int off = 1; off <= 8; off <<= 1)       // reduce over the 16 slots
        ss += __shfl_xor(ss, off, 64);
    float rn  = sqrtf(ss);
    float inv = (rn > 0.0f) ? 1.0f / rn : 0.0f;
    f16x4 h0v = ((const f16x4*)h0)[(size_t)n * 16 + t];
    float xi[4];
    #pragma unroll
    for (int j = 0; j < 4; ++j)
        xi[j] = (1.0f - ALPHA) * (xv[j] * inv) + ALPHA * (float)h0v[j];
    // y_f = sum_k xi_k * W[k][f], f = 4t+j; group g covers k in [16g,16g+16)
    float y[4] = {0.f, 0.f, 0.f, 0.f};
    #pragma unroll
    for (int m = 0; m < 16; ++m) {
        // xi_{16g+m} lives (replicated) at lane 4g + (m>>2), component m&3
        float xk = __shfl(xi[m & 3], 4 * g + (m >> 2), 64);
        const float4 w = *(const float4*)&sW[(16 * g + m) * NHID + 4 * t];
        y[0] = fmaf(xk, w.x, y[0]);
        y[1] = fmaf(xk, w.y, y[1]);
        y[2] = fmaf(xk, w.z, y[2]);
        y[3] = fmaf(xk, w.w, y[3]);
    }
    #pragma unroll
    for (int j = 0; j < 4; ++j) {                // sum the k-partitions
        y[j] += __shfl_xor(y[j], 16, 64);
        y[j] += __shfl_xor(y[j], 32, 64);
    }
    if (g == 0) {
        f16x4 o;
        #pragma unroll
        for (int j = 0; j < 4; ++j) {
            float v = fmaf(beta, y[j] - xi[j], xi[j]);   // (1-b)*xi + b*y
            o[j] = (f16)fmaxf(v, 0.0f);
        }
        ((f16x4*)h)[(size_t)n * 16 + t] = o;
    }
}

// out = h @ Wout + bout. One wave per row; lanes 0..39 hold the classes.
__global__ __launch_bounds__(256) void k_out(const f16* __restrict__ h,
                                             const float* __restrict__ Wout,
                                             const float* __restrict__ bout,
                                             float* __restrict__ out) {
    __shared__ float sW[NHID * NCLASS];  // 10 KB
    __shared__ float sb[NCLASS];
    for (int i = threadIdx.x; i < NHID * NCLASS; i += blockDim.x) sW[i] = Wout[i];
    if (threadIdx.x < NCLASS) sb[threadIdx.x] = bout[threadIdx.x];
    __syncthreads();
    const int wid = threadIdx.x >> 6;
    const int f   = threadIdx.x & 63;
    const int wpb = blockDim.x >> 6;
    const int c   = (f < NCLASS) ? f : 0;
    for (int n = blockIdx.x * wpb + wid; n < N_V; n += gridDim.x * wpb) {
        float hv = (float)h[(size_t)n * NHID + f];
        float y  = sb[c];
        #pragma unroll 8
        for (int k = 0; k < NHID; ++k)
            y = fmaf(__shfl(hv, k, 64), sW[k * NCLASS + c], y);
        if (f < NCLASS) out[(size_t)n * NCLASS + f] = y;
    }
}

// ---------------------------------------------------------------------------
extern "C" void kernel_launch(void* const* d_in, const int* in_sizes, int n_in,
                              void* d_out, int out_size, void* d_ws, size_t ws_size,
                              hipStream_t stream) {
    const float* x      = (const float*)d_in[0];
    const int*   vertex = (const int*)  d_in[1];
    const int*   edges  = (const int*)  d_in[2];
    const float* degE   = (const float*)d_in[3];
    const float* degV   = (const float*)d_in[4];
    const float* W0     = (const float*)d_in[5];
    const float* b0     = (const float*)d_in[6];
    const float* Ws     = (const float*)d_in[7];
    const float* Wout   = (const float*)d_in[8];
    const float* bout   = (const float*)d_in[9];
    float* out = (float*)d_out;

    // workspace carve-up (~66 MB)
    char* p = (char*)d_ws;
    auto carve = [&](size_t bytes) { char* r = p; p += (bytes + 255) & ~(size_t)255; return r; };
    f16*   h0      = (f16*)  carve((size_t)N_V * NHID * sizeof(f16));
    f16*   hA      = (f16*)  carve((size_t)N_V * NHID * sizeof(f16));
    f16*   Xe      = (f16*)  carve((size_t)N_E * NHID * sizeof(f16));
    float* factorE = (float*)carve((size_t)N_E * sizeof(float));
    int*   offE    = (int*)  carve((size_t)(N_E + 1) * sizeof(int));
    int*   offV    = (int*)  carve((size_t)(N_V + 1) * sizeof(int));
    int*   cntE    = (int*)  carve((size_t)N_E * sizeof(int));   // reused as cursor
    int*   cntV    = (int*)  carve((size_t)N_V * sizeof(int));   // reused as cursor
    int*   adjV    = (int*)  carve((size_t)NNZ_C * sizeof(int));
    int*   adjE    = (int*)  carve((size_t)NNZ_C * sizeof(int));
    int*   bsE     = (int*)  carve(256 * sizeof(int));
    int*   bsOffE  = (int*)  carve(256 * sizeof(int));
    int*   bsV     = (int*)  carve(256 * sizeof(int));
    int*   bsOffV  = (int*)  carve(256 * sizeof(int));

    const int scanBlocksE = (N_E + 1023) / 1024;   // 196
    const int scanBlocksV = (N_V + 1023) / 1024;   // 98

    // ---- one-time CSR build (per call) ----
    hipMemsetAsync(cntE, 0, (size_t)N_E * sizeof(int), stream);
    hipMemsetAsync(cntV, 0, (size_t)N_V * sizeof(int), stream);
    k_count2<<<(NNZ_C + 255) / 256, 256, 0, stream>>>(vertex, edges, cntE, cntV);

    k_scan_partial<<<scanBlocksE, 256, 0, stream>>>(cntE, offE, bsE, N_E);
    k_scan_partial<<<1,           256, 0, stream>>>(bsE, bsOffE, nullptr, scanBlocksE);
    k_scan_add    <<<scanBlocksE, 256, 0, stream>>>(offE, bsOffE, N_E);

    k_scan_partial<<<scanBlocksV, 256, 0, stream>>>(cntV, offV, bsV, N_V);
    k_scan_partial<<<1,           256, 0, stream>>>(bsV, bsOffV, nullptr, scanBlocksV);
    k_scan_add    <<<scanBlocksV, 256, 0, stream>>>(offV, bsOffV, N_V);

    k_factor<<<(N_E + 255) / 256, 256, 0, stream>>>(cntE, degE, factorE, offE, offV);

    hipMemsetAsync(cntE, 0, (size_t)N_E * sizeof(int), stream);
    hipMemsetAsync(cntV, 0, (size_t)N_V * sizeof(int), stream);
    k_fill<<<(NNZ_C + 255) / 256, 256, 0, stream>>>(vertex, edges, offE, offV,
                                                    cntE, cntV, adjV, adjE);

    // ---- network ----
    k_lin<<<2048, 256, 0, stream>>>(x, W0, b0, hA, h0);

    for (int i = 0; i < NLAYER; ++i) {
        float beta = (float)log(0.5 / (double)(i + 1) + 1.0);
        k_edge_gather  <<<(N_E + 3) / 4, 256, 0, stream>>>(offE, adjV, factorE, hA, Xe);
        k_vertex_update<<<(N_V + 3) / 4, 256, 0, stream>>>(offV, adjE, Xe, degV, h0,
                                                           Ws + (size_t)i * NHID * NHID,
                                                           beta, hA);
    }
    k_out<<<4096, 256, 0, stream>>>(hA, Wout, bout, out);
}

// Round 8
// 1260.969 us; speedup vs baseline: 5.3590x; 1.5958x over previous
//
#include <hip/hip_runtime.h>
#include <math.h>

#define N_V    100000
#define N_E    200000
#define NNZ_C  1600000
#define NFEAT  128
#define NHID   64
#define NCLASS 40
#define NLAYER 8
#define ALPHA  0.1f

typedef _Float16 f16;
typedef _Float16 f16x4 __attribute__((ext_vector_type(4)));

// ---------------------------------------------------------------------------
// histogram incidences per edge AND per vertex
__global__ __launch_bounds__(256) void k_count2(const int* __restrict__ vertex,
                                                const int* __restrict__ edges,
                                                int* __restrict__ cntE,
                                                int* __restrict__ cntV) {
    int z = blockIdx.x * blockDim.x + threadIdx.x;
    if (z < NNZ_C) {
        atomicAdd(&cntE[edges[z]], 1);
        atomicAdd(&cntV[vertex[z]], 1);
    }
}

// exclusive scan over n ints, 1024 elements per block (256 thr x 4 elems)
__global__ __launch_bounds__(256) void k_scan_partial(const int* __restrict__ in,
                                                      int* __restrict__ out,
                                                      int* __restrict__ blockSums,
                                                      int n) {
    __shared__ int sd[256];
    const int t = threadIdx.x;
    const int base = blockIdx.x * 1024 + t * 4;
    int v0 = (base + 0 < n) ? in[base + 0] : 0;
    int v1 = (base + 1 < n) ? in[base + 1] : 0;
    int v2 = (base + 2 < n) ? in[base + 2] : 0;
    int v3 = (base + 3 < n) ? in[base + 3] : 0;
    int s = v0 + v1 + v2 + v3;
    sd[t] = s;
    __syncthreads();
    #pragma unroll
    for (int off = 1; off < 256; off <<= 1) {
        int x = (t >= off) ? sd[t - off] : 0;
        __syncthreads();
        sd[t] += x;
        __syncthreads();
    }
    if (blockSums && t == 255) blockSums[blockIdx.x] = sd[255];
    int run = sd[t] - s;                 // exclusive prefix of this thread
    if (base + 0 < n) out[base + 0] = run; run += v0;
    if (base + 1 < n) out[base + 1] = run; run += v1;
    if (base + 2 < n) out[base + 2] = run; run += v2;
    if (base + 3 < n) out[base + 3] = run;
}

__global__ __launch_bounds__(256) void k_scan_add(int* __restrict__ data,
                                                  const int* __restrict__ bsOff,
                                                  int n) {
    const int base = blockIdx.x * 1024 + threadIdx.x * 4;
    const int add = bsOff[blockIdx.x];
    #pragma unroll
    for (int j = 0; j < 4; ++j)
        if (base + j < n) data[base + j] += add;
}

// factorE = degE / count; also finalize the CSR offset sentinels
__global__ __launch_bounds__(256) void k_factor(const int* __restrict__ counts,
                                                const float* __restrict__ degE,
                                                float* __restrict__ factorE,
                                                int* __restrict__ offE,
                                                int* __restrict__ offV) {
    int e = blockIdx.x * blockDim.x + threadIdx.x;
    if (e == 0) { offE[N_E] = NNZ_C; offV[N_V] = NNZ_C; }
    if (e < N_E) {
        int c = counts[e];
        factorE[e] = (c > 0) ? degE[e] / (float)c : 0.0f;
    }
}

// fill both adjacency lists (cursor order within a segment is arbitrary —
// only perturbs fp-sum rounding, well inside the tolerance)
__global__ __launch_bounds__(256) void k_fill(const int* __restrict__ vertex,
                                              const int* __restrict__ edges,
                                              const int* __restrict__ offE,
                                              const int* __restrict__ offV,
                                              int* __restrict__ curE,
                                              int* __restrict__ curV,
                                              int* __restrict__ adjV,
                                              int* __restrict__ adjE) {
    int z = blockIdx.x * blockDim.x + threadIdx.x;
    if (z < NNZ_C) {
        int v = vertex[z], e = edges[z];
        int pe = atomicAdd(&curE[e], 1);
        adjV[offE[e] + pe] = v;
        int pv = atomicAdd(&curV[v], 1);
        adjE[offV[v] + pv] = e;
    }
}

// h = relu(x @ W0 + b0) -> fp16; also copy to h0. One wave per row, lane = feature.
__global__ __launch_bounds__(256) void k_lin(const float* __restrict__ x,
                                             const float* __restrict__ W0,
                                             const float* __restrict__ b0,
                                             f16* __restrict__ h,
                                             f16* __restrict__ h0) {
    __shared__ float sW[NFEAT * NHID];   // 32 KB
    __shared__ float sb[NHID];
    for (int i = threadIdx.x; i < NFEAT * NHID; i += blockDim.x) sW[i] = W0[i];
    if (threadIdx.x < NHID) sb[threadIdx.x] = b0[threadIdx.x];
    __syncthreads();
    const int wid = threadIdx.x >> 6;
    const int f   = threadIdx.x & 63;
    const int wpb = blockDim.x >> 6;
    for (int n = blockIdx.x * wpb + wid; n < N_V; n += gridDim.x * wpb) {
        const float* xr = x + (size_t)n * NFEAT;
        float acc = sb[f];
        #pragma unroll 8
        for (int k = 0; k < NFEAT; ++k) acc = fmaf(xr[k], sW[k * NHID + f], acc);
        f16 r = (f16)fmaxf(acc, 0.0f);
        h [(size_t)n * NHID + f] = r;
        h0[(size_t)n * NHID + f] = r;
    }
}

// Xe[e] = (sum over incident vertices of h[v]) * factorE[e]
// GROUP-per-edge: each 16-lane group owns one edge; lane slot t holds f16x4
// (one full 128 B row per group per load). 4 independent segment chains per
// wave, no cross-group reduce. Masked 4-batch loop: min-clamped indices +
// 0/1-mask FMA (no serial scalar remainder).
__global__ __launch_bounds__(256) void k_edge_gather(const int* __restrict__ offE,
                                                     const int* __restrict__ adjV,
                                                     const float* __restrict__ factorE,
                                                     const f16* __restrict__ h,
                                                     f16* __restrict__ Xe) {
    const int lane = threadIdx.x & 63;
    const int g = lane >> 4, t = lane & 15;
    const int e = (blockIdx.x * 4 + (threadIdx.x >> 6)) * 4 + g;  // 16 edges/block
    if (e >= N_E) return;    // exact multiple anyway (200000 = 12500*16)
    const f16x4* __restrict__ hv = (const f16x4*)h;
    const int s   = offE[e];
    const int cnt = offE[e + 1] - s;
    const float fac = factorE[e];
    float acc[4] = {0.f, 0.f, 0.f, 0.f};
    for (int w = 0; w < cnt; w += 4) {
        int c1 = min(w + 1, cnt - 1);
        int c2 = min(w + 2, cnt - 1);
        int c3 = min(w + 3, cnt - 1);
        int i0 = adjV[s + w];            // broadcast within the group
        int i1 = adjV[s + c1];
        int i2 = adjV[s + c2];
        int i3 = adjV[s + c3];
        float m1 = (w + 1 < cnt) ? 1.f : 0.f;
        float m2 = (w + 2 < cnt) ? 1.f : 0.f;
        float m3 = (w + 3 < cnt) ? 1.f : 0.f;
        f16x4 v0 = hv[(size_t)i0 * 16 + t];
        f16x4 v1 = hv[(size_t)i1 * 16 + t];
        f16x4 v2 = hv[(size_t)i2 * 16 + t];
        f16x4 v3 = hv[(size_t)i3 * 16 + t];
        #pragma unroll
        for (int j = 0; j < 4; ++j) {
            acc[j] += (float)v0[j];
            acc[j] = fmaf(m1, (float)v1[j], acc[j]);
            acc[j] = fmaf(m2, (float)v2[j], acc[j]);
            acc[j] = fmaf(m3, (float)v3[j], acc[j]);
        }
    }
    f16x4 o;
    #pragma unroll
    for (int j = 0; j < 4; ++j) o[j] = (f16)(acc[j] * fac);
    ((f16x4*)Xe)[(size_t)e * 16 + t] = o;
}

// Fused: Xv = (sum over incident edges of Xe[e]) * degV  ->  L2 rownorm ->
// GCNII mix -> 64x64 GEMM -> relu -> fp16. GROUP-per-vertex (16 lanes each);
// norm reduce = 4 intra-group shuffles; GEMM broadcasts xi_k (1 shfl per k,
// uniform k-loop across groups).
__global__ __launch_bounds__(256) void k_vertex_update(const int* __restrict__ offV,
                                                       const int* __restrict__ adjE,
                                                       const f16* __restrict__ Xe,
                                                       const float* __restrict__ degV,
                                                       const f16* __restrict__ h0,
                                                       const float* __restrict__ Wi,
                                                       float beta,
                                                       f16* __restrict__ h) {
    __shared__ float sW[NHID * NHID];    // 16 KB, row-major [k][f]
    for (int i = threadIdx.x; i < NHID * NHID; i += blockDim.x) sW[i] = Wi[i];
    __syncthreads();
    const int lane = threadIdx.x & 63;
    const int g = lane >> 4, t = lane & 15;
    const int n = (blockIdx.x * 4 + (threadIdx.x >> 6)) * 4 + g; // 16 verts/block
    if (n >= N_V) return;    // exact multiple anyway (100000 = 6250*16)
    const f16x4* __restrict__ xe = (const f16x4*)Xe;
    const int s   = offV[n];
    const int cnt = offV[n + 1] - s;
    const float dv = degV[n];                                    // hoisted
    const f16x4 h0v = ((const f16x4*)h0)[(size_t)n * 16 + t];    // hoisted
    float acc[4] = {0.f, 0.f, 0.f, 0.f};
    for (int w = 0; w < cnt; w += 4) {
        int c1 = min(w + 1, cnt - 1);
        int c2 = min(w + 2, cnt - 1);
        int c3 = min(w + 3, cnt - 1);
        int i0 = adjE[s + w];
        int i1 = adjE[s + c1];
        int i2 = adjE[s + c2];
        int i3 = adjE[s + c3];
        float m1 = (w + 1 < cnt) ? 1.f : 0.f;
        float m2 = (w + 2 < cnt) ? 1.f : 0.f;
        float m3 = (w + 3 < cnt) ? 1.f : 0.f;
        f16x4 v0 = xe[(size_t)i0 * 16 + t];
        f16x4 v1 = xe[(size_t)i1 * 16 + t];
        f16x4 v2 = xe[(size_t)i2 * 16 + t];
        f16x4 v3 = xe[(size_t)i3 * 16 + t];
        #pragma unroll
        for (int j = 0; j < 4; ++j) {
            acc[j] += (float)v0[j];
            acc[j] = fmaf(m1, (float)v1[j], acc[j]);
            acc[j] = fmaf(m2, (float)v2[j], acc[j]);
            acc[j] = fmaf(m3, (float)v3[j], acc[j]);
        }
    }
    // scale by degV FIRST, then norm of the scaled row (matches reference)
    float xv[4], ss = 0.f;
    #pragma unroll
    for (int j = 0; j < 4; ++j) { xv[j] = acc[j] * dv; ss = fmaf(xv[j], xv[j], ss); }
    #pragma unroll
    for (int off = 1; off <= 8; off <<= 1)   // reduce within the 16-lane group
        ss += __shfl_xor(ss, off, 64);
    float rn  = sqrtf(ss);
    float inv = (rn > 0.0f) ? 1.0f / rn : 0.0f;
    float xi[4];
    #pragma unroll
    for (int j = 0; j < 4; ++j)
        xi[j] = (1.0f - ALPHA) * (xv[j] * inv) + ALPHA * (float)h0v[j];
    // y_f = sum_k xi_k * W[k][f], f = 4t+j; xi_k lives at lane 16g+(k>>2),
    // component k&3 (uniform k across groups -> LDS read is 2-way alias, free)
    float y[4] = {0.f, 0.f, 0.f, 0.f};
    #pragma unroll
    for (int k = 0; k < NHID; ++k) {
        float xk = __shfl(xi[k & 3], 16 * g + (k >> 2), 64);
        const float4 w = *(const float4*)&sW[k * NHID + 4 * t];
        y[0] = fmaf(xk, w.x, y[0]);
        y[1] = fmaf(xk, w.y, y[1]);
        y[2] = fmaf(xk, w.z, y[2]);
        y[3] = fmaf(xk, w.w, y[3]);
    }
    f16x4 o;
    #pragma unroll
    for (int j = 0; j < 4; ++j) {
        float v = fmaf(beta, y[j] - xi[j], xi[j]);   // (1-b)*xi + b*y
        o[j] = (f16)fmaxf(v, 0.0f);
    }
    ((f16x4*)h)[(size_t)n * 16 + t] = o;
}

// out = h @ Wout + bout. One wave per row; lanes 0..39 hold the classes.
__global__ __launch_bounds__(256) void k_out(const f16* __restrict__ h,
                                             const float* __restrict__ Wout,
                                             const float* __restrict__ bout,
                                             float* __restrict__ out) {
    __shared__ float sW[NHID * NCLASS];  // 10 KB
    __shared__ float sb[NCLASS];
    for (int i = threadIdx.x; i < NHID * NCLASS; i += blockDim.x) sW[i] = Wout[i];
    if (threadIdx.x < NCLASS) sb[threadIdx.x] = bout[threadIdx.x];
    __syncthreads();
    const int wid = threadIdx.x >> 6;
    const int f   = threadIdx.x & 63;
    const int wpb = blockDim.x >> 6;
    const int c   = (f < NCLASS) ? f : 0;
    for (int n = blockIdx.x * wpb + wid; n < N_V; n += gridDim.x * wpb) {
        float hv = (float)h[(size_t)n * NHID + f];
        float y  = sb[c];
        #pragma unroll 8
        for (int k = 0; k < NHID; ++k)
            y = fmaf(__shfl(hv, k, 64), sW[k * NCLASS + c], y);
        if (f < NCLASS) out[(size_t)n * NCLASS + f] = y;
    }
}

// ---------------------------------------------------------------------------
extern "C" void kernel_launch(void* const* d_in, const int* in_sizes, int n_in,
                              void* d_out, int out_size, void* d_ws, size_t ws_size,
                              hipStream_t stream) {
    const float* x      = (const float*)d_in[0];
    const int*   vertex = (const int*)  d_in[1];
    const int*   edges  = (const int*)  d_in[2];
    const float* degE   = (const float*)d_in[3];
    const float* degV   = (const float*)d_in[4];
    const float* W0     = (const float*)d_in[5];
    const float* b0     = (const float*)d_in[6];
    const float* Ws     = (const float*)d_in[7];
    const float* Wout   = (const float*)d_in[8];
    const float* bout   = (const float*)d_in[9];
    float* out = (float*)d_out;

    // workspace carve-up (~66 MB)
    char* p = (char*)d_ws;
    auto carve = [&](size_t bytes) { char* r = p; p += (bytes + 255) & ~(size_t)255; return r; };
    f16*   h0      = (f16*)  carve((size_t)N_V * NHID * sizeof(f16));
    f16*   hA      = (f16*)  carve((size_t)N_V * NHID * sizeof(f16));
    f16*   Xe      = (f16*)  carve((size_t)N_E * NHID * sizeof(f16));
    float* factorE = (float*)carve((size_t)N_E * sizeof(float));
    int*   offE    = (int*)  carve((size_t)(N_E + 1) * sizeof(int));
    int*   offV    = (int*)  carve((size_t)(N_V + 1) * sizeof(int));
    int*   cntE    = (int*)  carve((size_t)N_E * sizeof(int));   // reused as cursor
    int*   cntV    = (int*)  carve((size_t)N_V * sizeof(int));   // reused as cursor
    int*   adjV    = (int*)  carve((size_t)NNZ_C * sizeof(int));
    int*   adjE    = (int*)  carve((size_t)NNZ_C * sizeof(int));
    int*   bsE     = (int*)  carve(256 * sizeof(int));
    int*   bsOffE  = (int*)  carve(256 * sizeof(int));
    int*   bsV     = (int*)  carve(256 * sizeof(int));
    int*   bsOffV  = (int*)  carve(256 * sizeof(int));

    const int scanBlocksE = (N_E + 1023) / 1024;   // 196
    const int scanBlocksV = (N_V + 1023) / 1024;   // 98

    // ---- one-time CSR build (per call) ----
    hipMemsetAsync(cntE, 0, (size_t)N_E * sizeof(int), stream);
    hipMemsetAsync(cntV, 0, (size_t)N_V * sizeof(int), stream);
    k_count2<<<(NNZ_C + 255) / 256, 256, 0, stream>>>(vertex, edges, cntE, cntV);

    k_scan_partial<<<scanBlocksE, 256, 0, stream>>>(cntE, offE, bsE, N_E);
    k_scan_partial<<<1,           256, 0, stream>>>(bsE, bsOffE, nullptr, scanBlocksE);
    k_scan_add    <<<scanBlocksE, 256, 0, stream>>>(offE, bsOffE, N_E);

    k_scan_partial<<<scanBlocksV, 256, 0, stream>>>(cntV, offV, bsV, N_V);
    k_scan_partial<<<1,           256, 0, stream>>>(bsV, bsOffV, nullptr, scanBlocksV);
    k_scan_add    <<<scanBlocksV, 256, 0, stream>>>(offV, bsOffV, N_V);

    k_factor<<<(N_E + 255) / 256, 256, 0, stream>>>(cntE, degE, factorE, offE, offV);

    hipMemsetAsync(cntE, 0, (size_t)N_E * sizeof(int), stream);
    hipMemsetAsync(cntV, 0, (size_t)N_V * sizeof(int), stream);
    k_fill<<<(NNZ_C + 255) / 256, 256, 0, stream>>>(vertex, edges, offE, offV,
                                                    cntE, cntV, adjV, adjE);

    // ---- network ----
    k_lin<<<2048, 256, 0, stream>>>(x, W0, b0, hA, h0);

    for (int i = 0; i < NLAYER; ++i) {
        float beta = (float)log(0.5 / (double)(i + 1) + 1.0);
        k_edge_gather  <<<(N_E + 15) / 16, 256, 0, stream>>>(offE, adjV, factorE, hA, Xe);
        k_vertex_update<<<(N_V + 15) / 16, 256, 0, stream>>>(offV, adjE, Xe, degV, h0,
                                                             Ws + (size_t)i * NHID * NHID,
                                                             beta, hA);
    }
    k_out<<<4096, 256, 0, stream>>>(hA, Wout, bout, out);
}

// Round 9
// 1191.246 us; speedup vs baseline: 5.6727x; 1.0585x over previous
//
#include <hip/hip_runtime.h>
#include <math.h>

#define N_V    100000
#define N_E    200000
#define NNZ_C  1600000
#define NFEAT  128
#define NHID   64
#define NCLASS 40
#define NLAYER 8
#define ALPHA  0.1f

typedef _Float16 f16;
typedef _Float16 f16x8 __attribute__((ext_vector_type(8)));   // 16 B per lane

// ---------------------------------------------------------------------------
// histogram incidences per edge AND per vertex
__global__ __launch_bounds__(256) void k_count2(const int* __restrict__ vertex,
                                                const int* __restrict__ edges,
                                                int* __restrict__ cntE,
                                                int* __restrict__ cntV) {
    int z = blockIdx.x * blockDim.x + threadIdx.x;
    if (z < NNZ_C) {
        atomicAdd(&cntE[edges[z]], 1);
        atomicAdd(&cntV[vertex[z]], 1);
    }
}

// exclusive scan over n ints, 1024 elements per block (256 thr x 4 elems)
__global__ __launch_bounds__(256) void k_scan_partial(const int* __restrict__ in,
                                                      int* __restrict__ out,
                                                      int* __restrict__ blockSums,
                                                      int n) {
    __shared__ int sd[256];
    const int t = threadIdx.x;
    const int base = blockIdx.x * 1024 + t * 4;
    int v0 = (base + 0 < n) ? in[base + 0] : 0;
    int v1 = (base + 1 < n) ? in[base + 1] : 0;
    int v2 = (base + 2 < n) ? in[base + 2] : 0;
    int v3 = (base + 3 < n) ? in[base + 3] : 0;
    int s = v0 + v1 + v2 + v3;
    sd[t] = s;
    __syncthreads();
    #pragma unroll
    for (int off = 1; off < 256; off <<= 1) {
        int x = (t >= off) ? sd[t - off] : 0;
        __syncthreads();
        sd[t] += x;
        __syncthreads();
    }
    if (blockSums && t == 255) blockSums[blockIdx.x] = sd[255];
    int run = sd[t] - s;                 // exclusive prefix of this thread
    if (base + 0 < n) out[base + 0] = run; run += v0;
    if (base + 1 < n) out[base + 1] = run; run += v1;
    if (base + 2 < n) out[base + 2] = run; run += v2;
    if (base + 3 < n) out[base + 3] = run;
}

__global__ __launch_bounds__(256) void k_scan_add(int* __restrict__ data,
                                                  const int* __restrict__ bsOff,
                                                  int n) {
    const int base = blockIdx.x * 1024 + threadIdx.x * 4;
    const int add = bsOff[blockIdx.x];
    #pragma unroll
    for (int j = 0; j < 4; ++j)
        if (base + j < n) data[base + j] += add;
}

// factorE = degE / count; also finalize the CSR offset sentinels
__global__ __launch_bounds__(256) void k_factor(const int* __restrict__ counts,
                                                const float* __restrict__ degE,
                                                float* __restrict__ factorE,
                                                int* __restrict__ offE,
                                                int* __restrict__ offV) {
    int e = blockIdx.x * blockDim.x + threadIdx.x;
    if (e == 0) { offE[N_E] = NNZ_C; offV[N_V] = NNZ_C; }
    if (e < N_E) {
        int c = counts[e];
        factorE[e] = (c > 0) ? degE[e] / (float)c : 0.0f;
    }
}

// fill both adjacency lists (cursor order within a segment is arbitrary —
// only perturbs fp-sum rounding, well inside the tolerance)
__global__ __launch_bounds__(256) void k_fill(const int* __restrict__ vertex,
                                              const int* __restrict__ edges,
                                              const int* __restrict__ offE,
                                              const int* __restrict__ offV,
                                              int* __restrict__ curE,
                                              int* __restrict__ curV,
                                              int* __restrict__ adjV,
                                              int* __restrict__ adjE) {
    int z = blockIdx.x * blockDim.x + threadIdx.x;
    if (z < NNZ_C) {
        int v = vertex[z], e = edges[z];
        int pe = atomicAdd(&curE[e], 1);
        adjV[offE[e] + pe] = v;
        int pv = atomicAdd(&curV[v], 1);
        adjE[offV[v] + pv] = e;
    }
}

// h = relu(x @ W0 + b0) -> fp16; also copy to h0. One wave per row, lane = feature.
__global__ __launch_bounds__(256) void k_lin(const float* __restrict__ x,
                                             const float* __restrict__ W0,
                                             const float* __restrict__ b0,
                                             f16* __restrict__ h,
                                             f16* __restrict__ h0) {
    __shared__ float sW[NFEAT * NHID];   // 32 KB
    __shared__ float sb[NHID];
    for (int i = threadIdx.x; i < NFEAT * NHID; i += blockDim.x) sW[i] = W0[i];
    if (threadIdx.x < NHID) sb[threadIdx.x] = b0[threadIdx.x];
    __syncthreads();
    const int wid = threadIdx.x >> 6;
    const int f   = threadIdx.x & 63;
    const int wpb = blockDim.x >> 6;
    for (int n = blockIdx.x * wpb + wid; n < N_V; n += gridDim.x * wpb) {
        const float* xr = x + (size_t)n * NFEAT;
        float acc = sb[f];
        #pragma unroll 8
        for (int k = 0; k < NFEAT; ++k) acc = fmaf(xr[k], sW[k * NHID + f], acc);
        f16 r = (f16)fmaxf(acc, 0.0f);
        h [(size_t)n * NHID + f] = r;
        h0[(size_t)n * NHID + f] = r;
    }
}

// Xe[e] = (sum over incident vertices of h[v]) * factorE[e]
// 8-lane-SUBGROUP-per-edge: lane slot t in [0,8) holds f16x8 (16 B), so one
// wave load instruction gathers 8 random 128 B rows (1 KB/instr). 4-deep
// masked batch -> 32 rows in flight per wave, no cross-subgroup reduce.
__global__ __launch_bounds__(256) void k_edge_gather(const int* __restrict__ offE,
                                                     const int* __restrict__ adjV,
                                                     const float* __restrict__ factorE,
                                                     const f16* __restrict__ h,
                                                     f16* __restrict__ Xe) {
    const int lane = threadIdx.x & 63;
    const int sg = lane >> 3, t = lane & 7;
    const int e = (blockIdx.x * 4 + (threadIdx.x >> 6)) * 8 + sg;  // 32 edges/block
    if (e >= N_E) return;
    const f16x8* __restrict__ hv = (const f16x8*)h;
    const int s   = offE[e];
    const int cnt = offE[e + 1] - s;
    const float fac = factorE[e];
    float acc[8] = {0.f, 0.f, 0.f, 0.f, 0.f, 0.f, 0.f, 0.f};
    for (int w = 0; w < cnt; w += 4) {
        int c1 = min(w + 1, cnt - 1);
        int c2 = min(w + 2, cnt - 1);
        int c3 = min(w + 3, cnt - 1);
        int i0 = adjV[s + w];            // uniform within the subgroup
        int i1 = adjV[s + c1];
        int i2 = adjV[s + c2];
        int i3 = adjV[s + c3];
        float m1 = (w + 1 < cnt) ? 1.f : 0.f;
        float m2 = (w + 2 < cnt) ? 1.f : 0.f;
        float m3 = (w + 3 < cnt) ? 1.f : 0.f;
        f16x8 v0 = hv[(size_t)i0 * 8 + t];
        f16x8 v1 = hv[(size_t)i1 * 8 + t];
        f16x8 v2 = hv[(size_t)i2 * 8 + t];
        f16x8 v3 = hv[(size_t)i3 * 8 + t];
        #pragma unroll
        for (int j = 0; j < 8; ++j) {
            acc[j] += (float)v0[j];
            acc[j] = fmaf(m1, (float)v1[j], acc[j]);
            acc[j] = fmaf(m2, (float)v2[j], acc[j]);
            acc[j] = fmaf(m3, (float)v3[j], acc[j]);
        }
    }
    f16x8 o;
    #pragma unroll
    for (int j = 0; j < 8; ++j) o[j] = (f16)(acc[j] * fac);
    ((f16x8*)Xe)[(size_t)e * 8 + t] = o;
}

// Fused: Xv = (sum over incident edges of Xe[e]) * degV  ->  L2 rownorm ->
// GCNII mix -> 64x64 GEMM -> relu -> fp16. 8-lane-subgroup-per-vertex,
// 8-deep masked batch (avg vertex degree ~16) -> 64 rows in flight per wave.
__global__ __launch_bounds__(256) void k_vertex_update(const int* __restrict__ offV,
                                                       const int* __restrict__ adjE,
                                                       const f16* __restrict__ Xe,
                                                       const float* __restrict__ degV,
                                                       const f16* __restrict__ h0,
                                                       const float* __restrict__ Wi,
                                                       float beta,
                                                       f16* __restrict__ h) {
    __shared__ float sW[NHID * NHID];    // 16 KB, row-major [k][f]
    for (int i = threadIdx.x; i < NHID * NHID; i += blockDim.x) sW[i] = Wi[i];
    __syncthreads();
    const int lane = threadIdx.x & 63;
    const int sg = lane >> 3, t = lane & 7;
    const int n = (blockIdx.x * 4 + (threadIdx.x >> 6)) * 8 + sg; // 32 verts/block
    if (n >= N_V) return;
    const f16x8* __restrict__ xe = (const f16x8*)Xe;
    const int s   = offV[n];
    const int cnt = offV[n + 1] - s;
    const float dv = degV[n];
    const f16x8 h0v = ((const f16x8*)h0)[(size_t)n * 8 + t];
    float acc[8] = {0.f, 0.f, 0.f, 0.f, 0.f, 0.f, 0.f, 0.f};
    for (int w = 0; w < cnt; w += 8) {
        int   idx[8];
        float msk[8];
        f16x8 v[8];
        #pragma unroll
        for (int r = 0; r < 8; ++r) {
            int cr = min(w + r, cnt - 1);
            idx[r] = adjE[s + cr];
            msk[r] = (r == 0 || w + r < cnt) ? 1.f : 0.f;
        }
        #pragma unroll
        for (int r = 0; r < 8; ++r) v[r] = xe[(size_t)idx[r] * 8 + t];
        #pragma unroll
        for (int j = 0; j < 8; ++j) {
            #pragma unroll
            for (int r = 0; r < 8; ++r)
                acc[j] = fmaf(msk[r], (float)v[r][j], acc[j]);
        }
    }
    // scale by degV FIRST, then norm of the scaled row (matches reference)
    float xv[8], ss = 0.f;
    #pragma unroll
    for (int j = 0; j < 8; ++j) { xv[j] = acc[j] * dv; ss = fmaf(xv[j], xv[j], ss); }
    #pragma unroll
    for (int off = 1; off <= 4; off <<= 1)   // reduce within the 8-lane subgroup
        ss += __shfl_xor(ss, off, 64);
    float rn  = sqrtf(ss);
    float inv = (rn > 0.0f) ? 1.0f / rn : 0.0f;
    float xi[8];
    #pragma unroll
    for (int j = 0; j < 8; ++j)
        xi[j] = (1.0f - ALPHA) * (xv[j] * inv) + ALPHA * (float)h0v[j];
    // y_f = sum_k xi_k * W[k][f], f = 8t+j; xi_k owned by lane 8*sg+(k>>3),
    // component k&7. Uniform k-loop; LDS float4 reads are 2-way alias (free).
    float y[8] = {0.f, 0.f, 0.f, 0.f, 0.f, 0.f, 0.f, 0.f};
    #pragma unroll
    for (int k = 0; k < NHID; ++k) {
        float xk = __shfl(xi[k & 7], 8 * sg + (k >> 3), 64);
        const float4 wa = *(const float4*)&sW[k * NHID + 8 * t];
        const float4 wb = *(const float4*)&sW[k * NHID + 8 * t + 4];
        y[0] = fmaf(xk, wa.x, y[0]);
        y[1] = fmaf(xk, wa.y, y[1]);
        y[2] = fmaf(xk, wa.z, y[2]);
        y[3] = fmaf(xk, wa.w, y[3]);
        y[4] = fmaf(xk, wb.x, y[4]);
        y[5] = fmaf(xk, wb.y, y[5]);
        y[6] = fmaf(xk, wb.z, y[6]);
        y[7] = fmaf(xk, wb.w, y[7]);
    }
    f16x8 o;
    #pragma unroll
    for (int j = 0; j < 8; ++j) {
        float v = fmaf(beta, y[j] - xi[j], xi[j]);   // (1-b)*xi + b*y
        o[j] = (f16)fmaxf(v, 0.0f);
    }
    ((f16x8*)h)[(size_t)n * 8 + t] = o;
}

// out = h @ Wout + bout. One wave per row; lanes 0..39 hold the classes.
__global__ __launch_bounds__(256) void k_out(const f16* __restrict__ h,
                                             const float* __restrict__ Wout,
                                             const float* __restrict__ bout,
                                             float* __restrict__ out) {
    __shared__ float sW[NHID * NCLASS];  // 10 KB
    __shared__ float sb[NCLASS];
    for (int i = threadIdx.x; i < NHID * NCLASS; i += blockDim.x) sW[i] = Wout[i];
    if (threadIdx.x < NCLASS) sb[threadIdx.x] = bout[threadIdx.x];
    __syncthreads();
    const int wid = threadIdx.x >> 6;
    const int f   = threadIdx.x & 63;
    const int wpb = blockDim.x >> 6;
    const int c   = (f < NCLASS) ? f : 0;
    for (int n = blockIdx.x * wpb + wid; n < N_V; n += gridDim.x * wpb) {
        float hv = (float)h[(size_t)n * NHID + f];
        float y  = sb[c];
        #pragma unroll 8
        for (int k = 0; k < NHID; ++k)
            y = fmaf(__shfl(hv, k, 64), sW[k * NCLASS + c], y);
        if (f < NCLASS) out[(size_t)n * NCLASS + f] = y;
    }
}

// ---------------------------------------------------------------------------
extern "C" void kernel_launch(void* const* d_in, const int* in_sizes, int n_in,
                              void* d_out, int out_size, void* d_ws, size_t ws_size,
                              hipStream_t stream) {
    const float* x      = (const float*)d_in[0];
    const int*   vertex = (const int*)  d_in[1];
    const int*   edges  = (const int*)  d_in[2];
    const float* degE   = (const float*)d_in[3];
    const float* degV   = (const float*)d_in[4];
    const float* W0     = (const float*)d_in[5];
    const float* b0     = (const float*)d_in[6];
    const float* Ws     = (const float*)d_in[7];
    const float* Wout   = (const float*)d_in[8];
    const float* bout   = (const float*)d_in[9];
    float* out = (float*)d_out;

    // workspace carve-up (~66 MB)
    char* p = (char*)d_ws;
    auto carve = [&](size_t bytes) { char* r = p; p += (bytes + 255) & ~(size_t)255; return r; };
    f16*   h0      = (f16*)  carve((size_t)N_V * NHID * sizeof(f16));
    f16*   hA      = (f16*)  carve((size_t)N_V * NHID * sizeof(f16));
    f16*   Xe      = (f16*)  carve((size_t)N_E * NHID * sizeof(f16));
    float* factorE = (float*)carve((size_t)N_E * sizeof(float));
    int*   offE    = (int*)  carve((size_t)(N_E + 1) * sizeof(int));
    int*   offV    = (int*)  carve((size_t)(N_V + 1) * sizeof(int));
    int*   cntE    = (int*)  carve((size_t)N_E * sizeof(int));   // reused as cursor
    int*   cntV    = (int*)  carve((size_t)N_V * sizeof(int));   // reused as cursor
    int*   adjV    = (int*)  carve((size_t)NNZ_C * sizeof(int));
    int*   adjE    = (int*)  carve((size_t)NNZ_C * sizeof(int));
    int*   bsE     = (int*)  carve(256 * sizeof(int));
    int*   bsOffE  = (int*)  carve(256 * sizeof(int));
    int*   bsV     = (int*)  carve(256 * sizeof(int));
    int*   bsOffV  = (int*)  carve(256 * sizeof(int));

    const int scanBlocksE = (N_E + 1023) / 1024;   // 196
    const int scanBlocksV = (N_V + 1023) / 1024;   // 98

    // ---- one-time CSR build (per call) ----
    hipMemsetAsync(cntE, 0, (size_t)N_E * sizeof(int), stream);
    hipMemsetAsync(cntV, 0, (size_t)N_V * sizeof(int), stream);
    k_count2<<<(NNZ_C + 255) / 256, 256, 0, stream>>>(vertex, edges, cntE, cntV);

    k_scan_partial<<<scanBlocksE, 256, 0, stream>>>(cntE, offE, bsE, N_E);
    k_scan_partial<<<1,           256, 0, stream>>>(bsE, bsOffE, nullptr, scanBlocksE);
    k_scan_add    <<<scanBlocksE, 256, 0, stream>>>(offE, bsOffE, N_E);

    k_scan_partial<<<scanBlocksV, 256, 0, stream>>>(cntV, offV, bsV, N_V);
    k_scan_partial<<<1,           256, 0, stream>>>(bsV, bsOffV, nullptr, scanBlocksV);
    k_scan_add    <<<scanBlocksV, 256, 0, stream>>>(offV, bsOffV, N_V);

    k_factor<<<(N_E + 255) / 256, 256, 0, stream>>>(cntE, degE, factorE, offE, offV);

    hipMemsetAsync(cntE, 0, (size_t)N_E * sizeof(int), stream);
    hipMemsetAsync(cntV, 0, (size_t)N_V * sizeof(int), stream);
    k_fill<<<(NNZ_C + 255) / 256, 256, 0, stream>>>(vertex, edges, offE, offV,
                                                    cntE, cntV, adjV, adjE);

    // ---- network ----
    k_lin<<<2048, 256, 0, stream>>>(x, W0, b0, hA, h0);

    for (int i = 0; i < NLAYER; ++i) {
        float beta = (float)log(0.5 / (double)(i + 1) + 1.0);
        k_edge_gather  <<<(N_E + 31) / 32, 256, 0, stream>>>(offE, adjV, factorE, hA, Xe);
        k_vertex_update<<<(N_V + 31) / 32, 256, 0, stream>>>(offV, adjE, Xe, degV, h0,
                                                             Ws + (size_t)i * NHID * NHID,
                                                             beta, hA);
    }
    k_out<<<4096, 256, 0, stream>>>(hA, Wout, bout, out);
}